// Round 1
// baseline (244.604 us; speedup 1.0000x reference)
//
#include <hip/hip_runtime.h>

typedef unsigned short u16;
typedef __attribute__((ext_vector_type(8))) short short8;
typedef __attribute__((ext_vector_type(4))) float floatx4;

__device__ __forceinline__ u16 f32_to_bf16_rne(float f) {
  union { float f; unsigned int u; } v; v.f = f;
  unsigned int u = v.u;
  u += 0x7FFFu + ((u >> 16) & 1u);
  return (u16)(u >> 16);
}

__device__ __forceinline__ void load_lds_16(const void* gsrc, void* lds) {
  __builtin_amdgcn_global_load_lds(
      (const __attribute__((address_space(1))) unsigned int*)gsrc,
      (__attribute__((address_space(3))) unsigned int*)lds,
      16, 0, 0);
}

// ---------------- Kernel 1: global average pool ----------------
// grid 8192 = B*C blocks, 256 threads. pooled[b*256+c] = mean over 3136.
__global__ __launch_bounds__(256) void pool_kernel(const float* __restrict__ x,
                                                   float* __restrict__ pooled) {
  const int bc = blockIdx.x;
  const float4* row = (const float4*)(x + (size_t)bc * 3136);
  const int t = threadIdx.x;
  float s = 0.0f;
  for (int q = t; q < 784; q += 256) {   // 784 float4 = 3136 floats
    float4 v = row[q];
    s += (v.x + v.y) + (v.z + v.w);
  }
  #pragma unroll
  for (int off = 32; off > 0; off >>= 1) s += __shfl_down(s, off, 64);
  __shared__ float red[4];
  if ((t & 63) == 0) red[t >> 6] = s;
  __syncthreads();
  if (t == 0) pooled[bc] = (red[0] + red[1] + red[2] + red[3]) * (1.0f / 3136.0f);
}

// ---------------- Kernel 2: attention MLP + w_dyn (bf16) ----------------
// grid 256 = 32 b * 8 o-chunks, 256 threads.
__global__ __launch_bounds__(256) void attn_wdyn_kernel(
    const float* __restrict__ pooled, const float* __restrict__ weights,
    const float* __restrict__ w1, const float* __restrict__ b1,
    const float* __restrict__ w2, const float* __restrict__ b2,
    u16* __restrict__ wdyn) {
  const int blk = blockIdx.x;
  const int b = blk >> 3;
  const int oc = blk & 7;
  const int t = threadIdx.x;
  __shared__ float ph[256];
  __shared__ float hb[64];
  __shared__ float lg[8];
  ph[t] = pooled[b * 256 + t];
  __syncthreads();
  if (t < 64) {
    float acc = b1[t];
    const float* wr = w1 + t * 256;
    for (int c = 0; c < 256; ++c) acc += ph[c] * wr[c];
    hb[t] = fmaxf(acc, 0.0f);
  }
  __syncthreads();
  if (t < 8) {
    float acc = b2[t];
    const float* wr = w2 + t * 64;
    for (int j = 0; j < 64; ++j) acc += hb[j] * wr[j];
    lg[t] = acc;
  }
  __syncthreads();
  // every thread computes softmax redundantly from lg[8]
  float a[8];
  {
    float mx = lg[0];
    #pragma unroll
    for (int e = 1; e < 8; ++e) mx = fmaxf(mx, lg[e]);
    float sum = 0.0f;
    #pragma unroll
    for (int e = 0; e < 8; ++e) { a[e] = __expf(lg[e] - mx); sum += a[e]; }
    float inv = 1.0f / sum;
    #pragma unroll
    for (int e = 0; e < 8; ++e) a[e] *= inv;
  }
  const int o0 = oc * 32;
  // thread t owns column c=t for 32 output rows
  for (int i = 0; i < 32; ++i) {
    const int o = o0 + i;
    float acc = 0.0f;
    #pragma unroll
    for (int e = 0; e < 8; ++e)
      acc += a[e] * weights[((size_t)e * 256 + o) * 256 + t];
    wdyn[((size_t)b * 256 + o) * 256 + t] = f32_to_bf16_rne(acc);
  }
}

// ---------------- Kernel 3: batched GEMM out[b] = Wdyn[b] @ X[b] ----------------
// M=256 (o), N=3136 (spatial), K=256 (c). Tile 128x64x32, 4 waves, 16x16x32 bf16 MFMA.
#define BM 128
#define BN 64
#define BK 32
#define XP 40   // Xs pitch in u16 elements (80 B -> 20 dw mod 32 -> bank-uniform)

__global__ __launch_bounds__(256) void dynconv_gemm(const float* __restrict__ x,
                                                    const u16* __restrict__ wdyn,
                                                    float* __restrict__ out) {
  const int nb = blockIdx.x;   // 0..48
  const int mb = blockIdx.y;   // 0..1
  const int b  = blockIdx.z;   // 0..31
  const int t = threadIdx.x;
  const int lane = t & 63;
  const int wv = t >> 6;
  const int quad = lane >> 4;
  const int l16 = lane & 15;

  __shared__ u16 Ws[BM * BK];    // [m][k] pitch 32 elems (64 B)
  __shared__ u16 Xs[BN * XP];    // [n][k] pitch 40 elems (80 B)

  const float* xb = x + (size_t)b * (256 * 3136);
  const u16* wb = wdyn + ((size_t)b * 256 + mb * BM) * 256;
  float* ob = out + ((size_t)b * 256 + mb * BM) * 3136;
  const int n0 = nb * BN;

  floatx4 acc[2][4];
  #pragma unroll
  for (int i = 0; i < 2; ++i)
    #pragma unroll
    for (int j = 0; j < 4; ++j) acc[i][j] = (floatx4)(0.0f);

  const int xn = lane;   // n within tile (wave lanes span 64 consecutive n)
  const int xkg = wv;    // k-group (8 rows per wave)

  for (int kt = 0; kt < 8; ++kt) {
    const int k0 = kt * BK;
    // ---- stage W tile (bf16, [m][k] natural layout) via global_load_lds ----
    #pragma unroll
    for (int j = 0; j < 2; ++j) {
      const int i = j * 256 + t;   // 16B-chunk id 0..511
      const int r = i >> 2;        // row 0..127
      const int c8 = i & 3;        // 8-col group
      load_lds_16(wb + r * 256 + k0 + c8 * 8, &Ws[i * 8]);
    }
    // ---- stage X tile: 8 coalesced fp32 row-loads, cvt, one b128 LDS write ----
    {
      const float* xs = xb + (size_t)(k0 + xkg * 8) * 3136 + n0 + xn;
      short8 pk;
      #pragma unroll
      for (int j = 0; j < 8; ++j) {
        pk[j] = (short)f32_to_bf16_rne(xs[(size_t)j * 3136]);
      }
      *(short8*)(&Xs[xn * XP + xkg * 8]) = pk;
    }
    __syncthreads();
    // ---- MFMA compute ----
    short8 af[2];
    #pragma unroll
    for (int mt = 0; mt < 2; ++mt) {
      const int r = wv * 32 + mt * 16 + l16;
      af[mt] = *(const short8*)(&Ws[r * BK + quad * 8]);
    }
    short8 bfr[4];
    #pragma unroll
    for (int nt = 0; nt < 4; ++nt) {
      const int n = nt * 16 + l16;
      bfr[nt] = *(const short8*)(&Xs[n * XP + quad * 8]);
    }
    #pragma unroll
    for (int mt = 0; mt < 2; ++mt)
      #pragma unroll
      for (int nt = 0; nt < 4; ++nt)
        acc[mt][nt] = __builtin_amdgcn_mfma_f32_16x16x32_bf16(
            af[mt], bfr[nt], acc[mt][nt], 0, 0, 0);
    __syncthreads();
  }
  // ---- epilogue: C/D layout col=lane&15 (n), row=quad*4+reg (m) ----
  #pragma unroll
  for (int mt = 0; mt < 2; ++mt) {
    const int orow = wv * 32 + mt * 16 + quad * 4;
    #pragma unroll
    for (int nt = 0; nt < 4; ++nt) {
      const int n = n0 + nt * 16 + l16;
      #pragma unroll
      for (int r = 0; r < 4; ++r)
        ob[(size_t)(orow + r) * 3136 + n] = acc[mt][nt][r];
    }
  }
}

extern "C" void kernel_launch(void* const* d_in, const int* in_sizes, int n_in,
                              void* d_out, int out_size, void* d_ws, size_t ws_size,
                              hipStream_t stream) {
  const float* x       = (const float*)d_in[0];
  const float* weights = (const float*)d_in[1];
  const float* w1      = (const float*)d_in[2];
  const float* b1      = (const float*)d_in[3];
  const float* w2      = (const float*)d_in[4];
  const float* b2      = (const float*)d_in[5];
  float* out = (float*)d_out;

  float* pooled = (float*)d_ws;                       // 32 KB
  u16* wdyn = (u16*)((char*)d_ws + 32768);            // 4 MB bf16 [32][256][256]

  pool_kernel<<<8192, 256, 0, stream>>>(x, pooled);
  attn_wdyn_kernel<<<256, 256, 0, stream>>>(pooled, weights, w1, b1, w2, b2, wdyn);
  dynconv_gemm<<<dim3(49, 2, 32), 256, 0, stream>>>(x, wdyn, out);
}

// Round 2
// 231.468 us; speedup vs baseline: 1.0567x; 1.0567x over previous
//
#include <hip/hip_runtime.h>
#include <hip/hip_bf16.h>

typedef unsigned short u16;
typedef __attribute__((ext_vector_type(8))) short short8;
typedef __attribute__((ext_vector_type(4))) float floatx4;

__device__ __forceinline__ u16 f32_to_bf16_rne(float f) {
  union { float f; unsigned int u; } v; v.f = f;
  unsigned int u = v.u;
  u += 0x7FFFu + ((u >> 16) & 1u);
  return (u16)(u >> 16);
}

__device__ __forceinline__ void load_lds_16(const void* gsrc, void* lds) {
  __builtin_amdgcn_global_load_lds(
      (const __attribute__((address_space(1))) unsigned int*)gsrc,
      (__attribute__((address_space(3))) unsigned int*)lds,
      16, 0, 0);
}

// ---------------- Kernel 1: global average pool ----------------
// grid 8192 = B*C blocks, 256 threads. pooled[b*256+c] = mean over 3136.
__global__ __launch_bounds__(256) void pool_kernel(const float* __restrict__ x,
                                                   float* __restrict__ pooled) {
  const int bc = blockIdx.x;
  const float4* row = (const float4*)(x + (size_t)bc * 3136);
  const int t = threadIdx.x;
  float s = 0.0f;
  for (int q = t; q < 784; q += 256) {   // 784 float4 = 3136 floats
    float4 v = row[q];
    s += (v.x + v.y) + (v.z + v.w);
  }
  #pragma unroll
  for (int off = 32; off > 0; off >>= 1) s += __shfl_down(s, off, 64);
  __shared__ float red[4];
  if ((t & 63) == 0) red[t >> 6] = s;
  __syncthreads();
  if (t == 0) pooled[bc] = (red[0] + red[1] + red[2] + red[3]) * (1.0f / 3136.0f);
}

// ---------------- Kernel 2: attention MLP + w_dyn (bf16) ----------------
// grid 256 = 32 b * 8 o-chunks, 256 threads. MLP parallelized 4 threads/row.
__global__ __launch_bounds__(256) void attn_wdyn_kernel(
    const float* __restrict__ pooled, const float* __restrict__ weights,
    const float* __restrict__ w1, const float* __restrict__ b1,
    const float* __restrict__ w2, const float* __restrict__ b2,
    u16* __restrict__ wdyn) {
  const int blk = blockIdx.x;
  const int b = blk >> 3;
  const int oc = blk & 7;
  const int t = threadIdx.x;
  __shared__ float ph[256];
  __shared__ float part[256];
  __shared__ float hb[64];
  __shared__ float lg[8];
  ph[t] = pooled[b * 256 + t];
  __syncthreads();
  // h[row] partials: 4 threads per row, 64 c's each
  {
    const int row = t >> 2, seg = t & 3;
    const float* wr = w1 + row * 256 + seg * 64;
    const float* pp = ph + seg * 64;
    float a = 0.0f;
    #pragma unroll 8
    for (int c = 0; c < 64; ++c) a += pp[c] * wr[c];
    part[t] = a;
  }
  __syncthreads();
  if (t < 64) {
    float a = part[t * 4] + part[t * 4 + 1] + part[t * 4 + 2] + part[t * 4 + 3] + b1[t];
    hb[t] = fmaxf(a, 0.0f);
  }
  __syncthreads();
  // logits partials: 8 threads per expert, 8 j's each
  if (t < 64) {
    const int row = t >> 3, seg = t & 7;
    const float* wr = w2 + row * 64 + seg * 8;
    float a = 0.0f;
    #pragma unroll
    for (int j = 0; j < 8; ++j) a += hb[seg * 8 + j] * wr[j];
    part[t] = a;
  }
  __syncthreads();
  if (t < 8) {
    float a = b2[t];
    #pragma unroll
    for (int j = 0; j < 8; ++j) a += part[t * 8 + j];
    lg[t] = a;
  }
  __syncthreads();
  // every thread computes softmax redundantly from lg[8]
  float a[8];
  {
    float mx = lg[0];
    #pragma unroll
    for (int e = 1; e < 8; ++e) mx = fmaxf(mx, lg[e]);
    float sum = 0.0f;
    #pragma unroll
    for (int e = 0; e < 8; ++e) { a[e] = __expf(lg[e] - mx); sum += a[e]; }
    float inv = 1.0f / sum;
    #pragma unroll
    for (int e = 0; e < 8; ++e) a[e] *= inv;
  }
  const int o0 = oc * 32;
  // thread t owns column c=t for 32 output rows
  for (int i = 0; i < 32; ++i) {
    const int o = o0 + i;
    float acc = 0.0f;
    #pragma unroll
    for (int e = 0; e < 8; ++e)
      acc += a[e] * weights[((size_t)e * 256 + o) * 256 + t];
    wdyn[((size_t)b * 256 + o) * 256 + t] = f32_to_bf16_rne(acc);
  }
}

// ---------------- Kernel 3: batched GEMM out[b] = Wdyn[b] @ X[b] ----------------
// M=256 (o, full per block), N=3136 (spatial), K=256 (c).
// Tile 256x64x32, 4 waves (each owns 64 m-rows), 16x16x32 bf16 MFMA.
#define BM 256
#define BN 64
#define BK 32
#define XP 40   // Xs pitch in u16 elements (80 B)

__global__ __launch_bounds__(256) void dynconv_gemm(const float* __restrict__ x,
                                                    const u16* __restrict__ wdyn,
                                                    float* __restrict__ out) {
  const int nb = blockIdx.x;   // 0..48
  const int b  = blockIdx.y;   // 0..31
  const int t = threadIdx.x;
  const int lane = t & 63;
  const int wv = t >> 6;
  const int quad = lane >> 4;
  const int l16 = lane & 15;

  __shared__ u16 Ws[BM * BK];    // [m][k], pitch 32 elems (64 B) — lane-linear for load_lds
  __shared__ u16 Xs[BN * XP];    // [n][k], pitch 40 elems (80 B)

  const float* xb = x + (size_t)b * (256 * 3136);
  const u16* wb = wdyn + (size_t)b * 256 * 256;
  float* ob = out + (size_t)b * 256 * 3136;
  const int n0 = nb * BN;

  floatx4 acc[4][4];
  #pragma unroll
  for (int i = 0; i < 4; ++i)
    #pragma unroll
    for (int j = 0; j < 4; ++j) acc[i][j] = (floatx4)(0.0f);

  const int xn = lane;   // n within tile (wave lanes span 64 consecutive n)
  const int xkg = wv;    // k-group (8 rows per wave)

  for (int kt = 0; kt < 8; ++kt) {
    const int k0 = kt * BK;
    // ---- stage W tile (bf16, [m][k] natural layout) via global_load_lds ----
    #pragma unroll
    for (int j = 0; j < 4; ++j) {
      const int i = j * 256 + t;   // 16B-chunk id 0..1023
      const int r = i >> 2;        // row 0..255
      const int c8 = i & 3;        // 8-col group
      load_lds_16(wb + r * 256 + k0 + c8 * 8, &Ws[i * 8]);
    }
    // ---- stage X tile: 8 coalesced fp32 row-loads, pk-cvt, one b128 LDS write ----
    {
      const float* xs = xb + (size_t)(k0 + xkg * 8) * 3136 + n0 + xn;
      float v[8];
      #pragma unroll
      for (int j = 0; j < 8; ++j) v[j] = xs[(size_t)j * 3136];
      short8 pk;
      #pragma unroll
      for (int j = 0; j < 4; ++j) {
        __hip_bfloat162 h2 = __float22bfloat162_rn(make_float2(v[2 * j], v[2 * j + 1]));
        union { __hip_bfloat162 h; struct { short lo, hi; } s; } u; u.h = h2;
        pk[2 * j] = u.s.lo; pk[2 * j + 1] = u.s.hi;
      }
      *(short8*)(&Xs[xn * XP + xkg * 8]) = pk;
    }
    __syncthreads();
    // ---- MFMA compute: 4 m-tiles x 4 n-tiles per wave ----
    short8 bfr[4];
    #pragma unroll
    for (int nt = 0; nt < 4; ++nt) {
      const int n = nt * 16 + l16;
      bfr[nt] = *(const short8*)(&Xs[n * XP + quad * 8]);
    }
    #pragma unroll
    for (int mt = 0; mt < 4; ++mt) {
      const int r = wv * 64 + mt * 16 + l16;
      short8 af = *(const short8*)(&Ws[r * BK + quad * 8]);
      #pragma unroll
      for (int nt = 0; nt < 4; ++nt)
        acc[mt][nt] = __builtin_amdgcn_mfma_f32_16x16x32_bf16(
            af, bfr[nt], acc[mt][nt], 0, 0, 0);
    }
    __syncthreads();
  }
  // ---- epilogue: C/D layout col=lane&15 (n), row=quad*4+reg (m) ----
  #pragma unroll
  for (int mt = 0; mt < 4; ++mt) {
    const int orow = wv * 64 + mt * 16 + quad * 4;
    #pragma unroll
    for (int nt = 0; nt < 4; ++nt) {
      const int n = n0 + nt * 16 + l16;
      #pragma unroll
      for (int r = 0; r < 4; ++r)
        ob[(size_t)(orow + r) * 3136 + n] = acc[mt][nt][r];
    }
  }
}

extern "C" void kernel_launch(void* const* d_in, const int* in_sizes, int n_in,
                              void* d_out, int out_size, void* d_ws, size_t ws_size,
                              hipStream_t stream) {
  const float* x       = (const float*)d_in[0];
  const float* weights = (const float*)d_in[1];
  const float* w1      = (const float*)d_in[2];
  const float* b1      = (const float*)d_in[3];
  const float* w2      = (const float*)d_in[4];
  const float* b2      = (const float*)d_in[5];
  float* out = (float*)d_out;

  float* pooled = (float*)d_ws;                       // 32 KB
  u16* wdyn = (u16*)((char*)d_ws + 32768);            // 4 MB bf16 [32][256][256]

  pool_kernel<<<8192, 256, 0, stream>>>(x, pooled);
  attn_wdyn_kernel<<<256, 256, 0, stream>>>(pooled, weights, w1, b1, w2, b2, wdyn);
  dynconv_gemm<<<dim3(49, 32), 256, 0, stream>>>(x, wdyn, out);
}